// Round 13
// baseline (236.048 us; speedup 1.0000x reference)
//
#include <hip/hip_runtime.h>

// ---------------------------------------------------------------------------
// QCNN classifier: whole circuit == fixed 1024x1024 unitary U(weights).
// out[b,0] = 1 - 2*sum_{bit9(s)=1} |(U x_b)_s|^2 / ||x_b||^2   (qubit 0)
// out[b,1] = 1 - 2*sum_{bit7(s)=1} |(U x_b)_s|^2 / ||x_b||^2   (qubit 2)
// Only 768 of 1024 states needed (bit9|bit7) -> N=1536 GEMM (51.5 GF).
// R23 = R22 with the one-line base-fold fix. R22's absmax 1.004 was the
// +1.0 base added TWICE per row: (l&15)==0 lanes exist in both wc=0 and
// wc=1 waves (same rows, different column halves), and both added base in
// the colT==0 block -> out = 2-2p. Fix: base gated on (colT==0 && wc==0).
// Structure (audited clean): gemm stages A DIRECTLY from fp32 X (load
// 2xfloat4/lane -> f16 cvt -> ds_write_b128 to the byte-identical swizzled
// LDS address global_load_lds used; fragment path untouched from frozen
// R10). Row norms computed DURING staging (8-lane group covers the full
// 1024-elem row; xor-shuffle 1/2/4 + 128-float LDS table) -> prep kernel,
// nrm2, and the 32MB Xh intermediate all deleted. out: memset-0 +
// (colT==0 && wc==0) folds +1.0 into the atomicAdd. X L2 locality: the 12
// col-blocks of each row panel are consecutive on one XCD (L2-hit 11/12).
// No inter-block flags/spins; only stream ordering sim_build -> gemm_xn.
// ---------------------------------------------------------------------------

typedef _Float16 f16;
typedef f16 f16x8 __attribute__((ext_vector_type(8)));
typedef f16 f16x4 __attribute__((ext_vector_type(4)));
typedef f16 f16x2 __attribute__((ext_vector_type(2)));
typedef float f32x4 __attribute__((ext_vector_type(4)));

__device__ inline float2 cmul(float2 a, float2 b) {
    return make_float2(a.x * b.x - a.y * b.y, a.x * b.y + a.y * b.x);
}
__device__ inline float2 cadd(float2 a, float2 b) {
    return make_float2(a.x + b.x, a.y + b.y);
}

struct M2 { float2 m[4]; };

__device__ inline M2 m2_u3(float t, float p, float d) {
    float c = cosf(0.5f * t), s = sinf(0.5f * t);
    float2 ep = make_float2(cosf(p), sinf(p));
    float2 ed = make_float2(cosf(d), sinf(d));
    M2 U;
    U.m[0] = make_float2(c, 0.f);
    U.m[1] = make_float2(-ed.x * s, -ed.y * s);
    U.m[2] = make_float2(ep.x * s, ep.y * s);
    float2 epd = cmul(ep, ed);
    U.m[3] = make_float2(epd.x * c, epd.y * c);
    return U;
}
__device__ inline M2 m2_ry(float t) {
    float c = cosf(0.5f * t), s = sinf(0.5f * t);
    M2 U;
    U.m[0] = make_float2(c, 0.f);  U.m[1] = make_float2(-s, 0.f);
    U.m[2] = make_float2(s, 0.f);  U.m[3] = make_float2(c, 0.f);
    return U;
}
__device__ inline M2 m2_rz(float t) {
    float c = cosf(0.5f * t), s = sinf(0.5f * t);
    M2 U;
    U.m[0] = make_float2(c, -s); U.m[1] = make_float2(0.f, 0.f);
    U.m[2] = make_float2(0.f, 0.f); U.m[3] = make_float2(c, s);
    return U;
}
__device__ inline M2 m2_rx(float t) {
    float c = cosf(0.5f * t), s = sinf(0.5f * t);
    M2 U;
    U.m[0] = make_float2(c, 0.f);   U.m[1] = make_float2(0.f, -s);
    U.m[2] = make_float2(0.f, -s);  U.m[3] = make_float2(c, 0.f);
    return U;
}

__device__ inline void ap2x2(float2& x, float2& y, const M2& U) {
    float2 nx = cadd(cmul(U.m[0], x), cmul(U.m[1], y));
    float2 ny = cadd(cmul(U.m[2], x), cmul(U.m[3], y));
    x = nx; y = ny;
}
__device__ inline void apA(float2 v[4], const M2& U) { ap2x2(v[0], v[2], U); ap2x2(v[1], v[3], U); }
__device__ inline void apB(float2 v[4], const M2& U) { ap2x2(v[0], v[1], U); ap2x2(v[2], v[3], U); }
__device__ inline void swapv(float2& a, float2& b) { float2 t = a; a = b; b = t; }

__device__ inline void conv_col(const float* w, float2 v[4]) {
    apA(v, m2_u3(w[0], w[1], w[2]));
    apB(v, m2_u3(w[3], w[4], w[5]));
    swapv(v[2], v[3]);                    // cnot (control=a)
    apA(v, m2_ry(w[6]));
    apB(v, m2_rz(w[7]));
    swapv(v[1], v[3]);                    // cnot (control=b)
    apA(v, m2_ry(w[8]));
    swapv(v[2], v[3]);                    // cnot (control=a)
    apA(v, m2_u3(w[9], w[10], w[11]));
    apB(v, m2_u3(w[12], w[13], w[14]));
}
__device__ inline void pool_col(const float* p, float2 v[4]) {
    {   // crz(p0): diag(1,1,e^{-ip0/2},e^{+ip0/2})
        float c = cosf(0.5f * p[0]), s = sinf(0.5f * p[0]);
        v[2] = cmul(v[2], make_float2(c, -s));
        v[3] = cmul(v[3], make_float2(c, s));
    }
    swapv(v[0], v[2]); swapv(v[1], v[3]); // X on a
    {   // crx(p1) on (v2,v3)
        M2 U = m2_rx(p[1]);
        ap2x2(v[2], v[3], U);
    }
}

__device__ __forceinline__ void glds16(const void* g, void* l) {
    __builtin_amdgcn_global_load_lds(
        (const __attribute__((address_space(1))) void*)g,
        (__attribute__((address_space(3))) void*)l, 16, 0, 0);
}

// ---------------------------------------------------------------------------
// Kernel A: sim (R17's passing structure). grid 256 x 512 thr.
// In-LDS gate build (threads<108), 4 U-columns/block (2 cols/thread),
// f16x4 stores into BTh [n'][1024] with XCD-group t-swizzle.
// ---------------------------------------------------------------------------
__global__ __launch_bounds__(512) void sim_build(const float* __restrict__ wc1,
                                                 const float* __restrict__ wc2,
                                                 const float* __restrict__ wp1,
                                                 const float* __restrict__ wp2,
                                                 const float* __restrict__ wfc,
                                                 f16* __restrict__ BTh) {
    __shared__ float2 st[4][1025];   // [col][state], +1 pad
    __shared__ float2 gmL[27 * 16];
    __shared__ int2   gpL[27];
    const int tid = threadIdx.x;
    const int sb = blockIdx.x;
    const int t0 = (sb & 7) * 128 + (sb >> 3) * 4;   // XCD-group swizzle

    for (int i = tid; i < 1024; i += 512) {
#pragma unroll
        for (int c = 0; c < 4; c++)
            st[c][i] = make_float2((i == t0 + c) ? 1.f : 0.f, 0.f);
    }

    if (tid < 108) {
        const int n = tid >> 2, c = tid & 3;
        float2 v[4];
        for (int i = 0; i < 4; i++) v[i] = make_float2(0.f, 0.f);
        v[c] = make_float2(1.f, 0.f);

        int a, b;
        if (n < 5)        { int i = 2*n;       a = i;   b = i+1; conv_col(wc1 + 15*i, v); }
        else if (n < 9)   { int i = 2*(n-5)+1; a = i;   b = i+1; conv_col(wc1 + 15*i, v); }
        else if (n == 9)  { a = 0; b = 9;      conv_col(wc1 + 105, v); }
        else if (n < 15)  { int idx = n-10, i = 2*idx; a = i+1; b = i; pool_col(wp1 + 2*idx, v); }
        else if (n < 19)  { int idx = n-15, i = 2*idx; a = i; b = i+2; conv_col(wc2 + 15*idx, v); }
        else if (n == 19) { a = 2; b = 0;      pool_col(wp2 + 0, v); }
        else if (n == 20) { a = 6; b = 4;      pool_col(wp2 + 2, v); }
        else if (n <= 23) { // CNOTs (control = a)
            a = (n == 21) ? 0 : (n == 22) ? 2 : 4;
            b = (n == 23) ? 0 : 4;
            swapv(v[2], v[3]);
        } else {            // RX on qubit a
            a = (n == 24) ? 0 : (n == 25) ? 2 : 4;
            b = a + 1;
            apA(v, m2_rx(wfc[n - 24]));
        }
        if (c == 0) gpL[n] = make_int2(9 - a, 9 - b);   // qubit q -> bit (9-q)
        for (int i = 0; i < 4; i++) gmL[n * 16 + i * 4 + c] = v[i];
    }
    __syncthreads();

    const int cg = tid >> 8;          // 0..1: cols {2cg, 2cg+1}
    const int q = tid & 255;          // quad index
    for (int g = 0; g < 27; g++) {
        const int2 p = gpL[g];
        float2 m[16];
#pragma unroll
        for (int i = 0; i < 16; i++) m[i] = gmL[g * 16 + i];   // LDS broadcast
        const int p1 = p.x, p2 = p.y;
        const int lo = min(p1, p2), hi = max(p1, p2);
        const int m1 = (1 << lo) - 1;
        int tt = (q & m1) | ((q & ~m1) << 1);
        const int m2m = (1 << hi) - 1;
        const int i0 = (tt & m2m) | ((tt & ~m2m) << 1);
        int idx[4];
        for (int ga = 0; ga < 2; ga++)
            for (int gb = 0; gb < 2; gb++)
                idx[2 * ga + gb] = i0 | (ga << p1) | (gb << p2);
#pragma unroll
        for (int cc = 0; cc < 2; cc++) {
            const int c = 2 * cg + cc;
            float2 v[4];
#pragma unroll
            for (int i = 0; i < 4; i++) v[i] = st[c][idx[i]];
#pragma unroll
            for (int i = 0; i < 4; i++) {
                float2 s = make_float2(0.f, 0.f);
#pragma unroll
                for (int j = 0; j < 4; j++) s = cadd(s, cmul(m[i * 4 + j], v[j]));
                st[c][idx[i]] = s;       // in-place: quad is thread-private
            }
        }
        __syncthreads();
    }

    // f16x4 store into BTh [n'][1024] at columns t0..t0+3.
    // n' < 768 = Re, else Im; n' % 768 = grp*256 + pos,
    // grp: (b9,b7)=(1,0)->0, (1,1)->1, (0,1)->2; pos = bit8(s)*128 | (s&127).
    for (int s = tid; s < 1024; s += 512) {
        const int b9 = (s >> 9) & 1, b7 = (s >> 7) & 1;
        if (b9 | b7) {
            const int grp = b9 ? b7 : 2;
            const int pos = (((s >> 8) & 1) << 7) | (s & 127);
            const int np = grp * 256 + pos;
            f16x4 re, im;
#pragma unroll
            for (int c = 0; c < 4; c++) {
                re[c] = (f16)st[c][s].x;
                im[c] = (f16)st[c][s].y;
            }
            *(f16x4*)(BTh + (size_t)np * 1024 + t0) = re;
            *(f16x4*)(BTh + (size_t)(np + 768) * 1024 + t0) = im;
        }
    }
}

// ---------------------------------------------------------------------------
// Kernel B: gemm staging A directly from fp32 X, with in-staging row norms.
// grid 1536 x 256 thr. Tile/fragment geometry = FROZEN R10 kernel.
// out = memset-0; (colT==0 && wc==0) folds +1.0 into the atomicAdd.
// ---------------------------------------------------------------------------
__global__ __launch_bounds__(256) void gemm_xn(const float* __restrict__ X,
                                               const f16* __restrict__ Bt,
                                               float* __restrict__ out) {
    __shared__ char Ash[16384];
    __shared__ char Bsh[16384];
    __shared__ float nrmL[128];
    const int tid = threadIdx.x;
    const int l = tid & 63, w = tid >> 6;
    const int wr = w >> 1, wc = w & 1;

    // decode (R13-verified algebra): XCD x owns row panels {x, x+8, ...};
    // the 12 col-blocks of a panel are consecutive on one XCD -> X panel
    // is L2-hit 11/12 times.
    const int lin = blockIdx.x;              // 0..1535
    const int xcd = lin & 7;
    const int mm = lin >> 3;                 // 0..191
    const int rowT = xcd + 8 * (mm / 12);    // 0..127
    const int colT = mm % 12;                // 0..11
    const int row0 = rowT * 128, col0 = colT * 128;

    // staging geometry (identical to R10): wave w owns rows [32w, 32w+32);
    // lane l -> row +(l>>3) (+8g per glds group), phys chunk l&7,
    // pre-swizzled source chunk kc = (l&7) ^ (row&7).
    const int srow = l >> 3;                       // 0..7
    const int kc = (l & 7) ^ (srow & 7);           // logical chunk (8 elems)
    const float* xS = X + (size_t)(row0 + 32 * w + srow) * 1024 + kc * 8;
    const f16*   bS = Bt + (size_t)(col0 + 32 * w + srow) * 1024 + kc * 8;
    char* aD = Ash + (32 * w) * 128 + l * 16;      // per-lane dest (== glds16's)
    char* bD = Bsh + (32 * w) * 128;

    // fragment ds_read offsets: m = wr*64 + i*16 + (l&15), k-half h:
    // c_log = (l>>4) + 4h, phys = c_log ^ (m&7) = c_log ^ (l&7)
    int aOff[4][2], bOff[4][2];
#pragma unroll
    for (int i = 0; i < 4; i++)
#pragma unroll
        for (int h = 0; h < 2; h++) {
            const int cphys = (((l >> 4) + 4 * h) ^ (l & 7));
            aOff[i][h] = (wr * 64 + i * 16 + (l & 15)) * 128 + cphys * 16;
            bOff[i][h] = (wc * 64 + i * 16 + (l & 15)) * 128 + cphys * 16;
        }

    f32x4 acc[4][4];
    const f32x4 z = {0.f, 0.f, 0.f, 0.f};
#pragma unroll
    for (int i = 0; i < 4; i++)
#pragma unroll
        for (int j = 0; j < 4; j++) acc[i][j] = z;

    float sq[4] = {0.f, 0.f, 0.f, 0.f};    // row-partial sum of squares (per g)

    for (int k0 = 0; k0 < 1024; k0 += 64) {
        // B: async global->LDS (4 glds)
#pragma unroll
        for (int g = 0; g < 4; g++)
            glds16(bS + k0 + g * 8 * 1024, bD + g * 1024);
        // A: fp32 load -> f16 cvt -> ds_write (same LDS bytes glds16 wrote)
#pragma unroll
        for (int g = 0; g < 4; g++) {
            const float* p = xS + k0 + g * 8 * 1024;
            const float4 xa = *(const float4*)p;
            const float4 xb = *(const float4*)(p + 4);
            sq[g] += xa.x * xa.x + xa.y * xa.y + xa.z * xa.z + xa.w * xa.w
                   + xb.x * xb.x + xb.y * xb.y + xb.z * xb.z + xb.w * xb.w;
            f16x8 h;
            h[0] = (f16)xa.x; h[1] = (f16)xa.y; h[2] = (f16)xa.z; h[3] = (f16)xa.w;
            h[4] = (f16)xb.x; h[5] = (f16)xb.y; h[6] = (f16)xb.z; h[7] = (f16)xb.w;
            *(f16x8*)(aD + g * 1024) = h;
        }
        __syncthreads();     // drains B glds (vmcnt) + A ds_writes (lgkm)
#pragma unroll
        for (int h = 0; h < 2; h++) {
            f16x8 af[4], bf[4];
#pragma unroll
            for (int i = 0; i < 4; i++) {
                af[i] = *(const f16x8*)(Ash + aOff[i][h]);
                bf[i] = *(const f16x8*)(Bsh + bOff[i][h]);
            }
#pragma unroll
            for (int mi = 0; mi < 4; mi++)
#pragma unroll
                for (int ni = 0; ni < 4; ni++)
                    acc[mi][ni] = __builtin_amdgcn_mfma_f32_16x16x32_f16(
                        af[mi], bf[ni], acc[mi][ni], 0, 0, 0);
        }
        __syncthreads();
    }

    // ---- row norms: 8 lanes (same srow) hold disjoint chunk-partials ----
#pragma unroll
    for (int g = 0; g < 4; g++) {
        sq[g] += __shfl_xor(sq[g], 1, 64);
        sq[g] += __shfl_xor(sq[g], 2, 64);
        sq[g] += __shfl_xor(sq[g], 4, 64);
    }
    if ((l & 7) == 0) {
#pragma unroll
        for (int g = 0; g < 4; g++)
            nrmL[32 * w + 8 * g + srow] = sq[g];
    }
    __syncthreads();

    // fused epilogue: group-weighted squares, 16-lane reduce, atomics.
    // Base +1.0 folded by exactly ONE lane-set per row: colT==0 AND wc==0
    // (wc=0 and wc=1 waves cover the same rows -> gate on wc).
    float c0[4][4], c1[4][4];   // [mi][reg-row]
#pragma unroll
    for (int mi = 0; mi < 4; mi++)
#pragma unroll
        for (int rr = 0; rr < 4; rr++) { c0[mi][rr] = 0.f; c1[mi][rr] = 0.f; }
#pragma unroll
    for (int ni = 0; ni < 4; ni++) {
        const int n_glob = col0 + wc * 64 + ni * 16 + (l & 15);
        const int nm = (n_glob >= 768) ? n_glob - 768 : n_glob;
        const int grp = nm >> 8;               // 0: b9 only, 1: both, 2: b7 only
        const float w0 = (grp <= 1) ? 1.f : 0.f;
        const float w1 = (grp >= 1) ? 1.f : 0.f;
#pragma unroll
        for (int mi = 0; mi < 4; mi++)
#pragma unroll
            for (int rr = 0; rr < 4; rr++) {
                const float y = acc[mi][ni][rr];
                const float y2 = y * y;
                c0[mi][rr] += w0 * y2;
                c1[mi][rr] += w1 * y2;
            }
    }
#pragma unroll
    for (int off = 1; off < 16; off <<= 1)
#pragma unroll
        for (int mi = 0; mi < 4; mi++)
#pragma unroll
            for (int rr = 0; rr < 4; rr++) {
                c0[mi][rr] += __shfl_xor(c0[mi][rr], off, 64);
                c1[mi][rr] += __shfl_xor(c1[mi][rr], off, 64);
            }
    if ((l & 15) == 0) {
        const float base = (colT == 0 && wc == 0) ? 1.0f : 0.0f;
        const int q = l >> 4;
#pragma unroll
        for (int mi = 0; mi < 4; mi++)
#pragma unroll
            for (int rr = 0; rr < 4; rr++) {
                const int ri = wr * 64 + mi * 16 + q * 4 + rr;   // 0..127
                const int row = row0 + ri;
                const float inv = -2.0f / nrmL[ri];
                atomicAdd(&out[row * 2 + 0], fmaf(c0[mi][rr], inv, base));
                atomicAdd(&out[row * 2 + 1], fmaf(c1[mi][rr], inv, base));
            }
    }
}

extern "C" void kernel_launch(void* const* d_in, const int* in_sizes, int n_in,
                              void* d_out, int out_size, void* d_ws, size_t ws_size,
                              hipStream_t stream) {
    const float* x   = (const float*)d_in[0];   // 16384 x 1024
    const float* wc1 = (const float*)d_in[1];   // 10 x 15
    const float* wc2 = (const float*)d_in[2];   // 4 x 15
    const float* wp1 = (const float*)d_in[3];   // 5 x 2
    const float* wp2 = (const float*)d_in[4];   // 2 x 2
    const float* wfc = (const float*)d_in[5];   // 3
    float* out = (float*)d_out;                 // 16384 x 2

    uintptr_t wsp = (uintptr_t)d_ws;
    f16* BTh = (f16*)(wsp + 8192);              // 3 MB (1536 x 1024)

    hipMemsetAsync(out, 0, 16384 * 2 * sizeof(float), stream);
    sim_build<<<256, 512, 0, stream>>>(wc1, wc2, wp1, wp2, wfc, BTh);
    gemm_xn<<<1536, 256, 0, stream>>>(x, BTh, out);
}